// Round 20
// baseline (29.909 us; speedup 1.0000x reference)
//
#include <hip/hip_runtime.h>
#include <math.h>

// Chamfer loss, B=8, C=3, M=N=4096, fp32 — MFMA, round 20.
//
// sq[m][n] = s2[m] + d2[n] - 2 s.d as a K=16 bf16 GEMM with hi/lo split:
//   A_m = [-2xh,-2xh,-2xl,-2xl | y.. | z.. | s2h,s2l,1,1]   (query rows)
//   B_n = [ xh,  xl,  xh,  xl  | y.. | z.. | 1,1,d2h,d2l]   (reference cols)
// C layout (m74/m101): col = lane&31, row = (reg&3) + 8*(reg>>2) + 4*(lane>>5)
//
// Round-20 = round-16 main (22.0 us best — converged: occupancy 4w/SIMD
// optimal r10/r19, XOR swizzle r16, plain E/O v_min chains, min3 banned r14)
// + dispatch fusion: chamfer_final folded into chamfer_reduce via 3 scaled
// atomicAdds per block (768 atomics total — negligible; r3's lesson was
// about 2M+). out[] zero-init by main's block 0 (stream ordering: main
// completes before reduce starts). Graph: 3 nodes -> 2. Zero memsets.

constexpr int B = 8;
constexpr int M = 4096;   // == N

typedef __attribute__((ext_vector_type(8)))  short bf16x8;
typedef __attribute__((ext_vector_type(16))) float f32x16;

__device__ inline unsigned short bf16_of(float x) {   // round-to-nearest-even
    unsigned int u = __float_as_uint(x);
    u += 0x7FFFu + ((u >> 16) & 1u);
    return (unsigned short)(u >> 16);
}
__device__ inline float bf16_to_f(unsigned short h) {
    return __uint_as_float(((unsigned int)h) << 16);
}

// ws: part [2 cs][16 db][M] f32 @ 0   (512 KB)

// grid 1024 = (dir<<9 | b<<6 | rg<<1 | cs); 256 thr = 4 waves
// wave w: rows rg*128 + w*32 .. +32 ; cols cs*2048 .. +2048 (2 chunks of 1024)
__global__ __launch_bounds__(256, 4) void chamfer_main(
    const float* __restrict__ src,
    const float* __restrict__ dst,
    float* __restrict__ part,
    float* __restrict__ out)
{
    // zero-init out for the reduce pass (runs after main via stream order)
    if (blockIdx.x == 0 && threadIdx.x < 3) out[threadIdx.x] = 0.0f;

    int bid = blockIdx.x;
    const int cs  = bid & 1;  bid >>= 1;
    const int rg  = bid & 31; bid >>= 5;
    const int b   = bid & 7;  bid >>= 3;
    const int dir = bid;      // 0: rows=src scan dst ; 1: rows=dst scan src

    const float* __restrict__ qry = dir ? dst : src;   // A-side (rows)
    const float* __restrict__ ref = dir ? src : dst;   // B-side (cols)

    const int tid  = threadIdx.x;
    const int wave = tid >> 6;
    const int l31  = tid & 31;
    const int hf   = (tid >> 5) & 1;    // k-group / row-half within wave

    __shared__ __align__(16) unsigned short bstage[2][1024][8];  // 32 KB

    // per-lane swizzled read rows: col i*64+l31 -> i*64 + sA ; +32 -> i*64 + sB
    const int sA = l31 ^ (l31 >> 3);
    const int sB = 32 + (l31 ^ (4 | (l31 >> 3)));

    // ---- augmented A fragment for this lane's row (constant across scan) ----
    bf16x8 afrag;
    {
        const int mrow = rg * 128 + wave * 32 + l31;
        const float* qb = qry + (size_t)b * 3 * M;
        const float x = qb[0 * M + mrow];
        const float y = qb[1 * M + mrow];
        const float z = qb[2 * M + mrow];
        const float s2 = x * x + y * y + z * z;
        const float xhf = bf16_to_f(bf16_of(x));
        const float yhf = bf16_to_f(bf16_of(y));
        const float zhf = bf16_to_f(bf16_of(z));
        // -2*hi exact (pow2 scale of a bf16 value)
        const unsigned short nxh = bf16_of(-2.0f * xhf), nxl = bf16_of(-2.0f * (x - xhf));
        const unsigned short nyh = bf16_of(-2.0f * yhf), nyl = bf16_of(-2.0f * (y - yhf));
        const unsigned short nzh = bf16_of(-2.0f * zhf), nzl = bf16_of(-2.0f * (z - zhf));
        const unsigned short s2h = bf16_of(s2);
        const unsigned short s2l = bf16_of(s2 - bf16_to_f(s2h));
        const unsigned short one = 0x3F80;
        bf16x8 alo, ahi;
        alo[0]=(short)nxh; alo[1]=(short)nxh; alo[2]=(short)nxl; alo[3]=(short)nxl;
        alo[4]=(short)nyh; alo[5]=(short)nyh; alo[6]=(short)nyl; alo[7]=(short)nyl;
        ahi[0]=(short)nzh; ahi[1]=(short)nzh; ahi[2]=(short)nzl; ahi[3]=(short)nzl;
        ahi[4]=(short)s2h; ahi[5]=(short)s2l; ahi[6]=(short)one; ahi[7]=(short)one;
        afrag = hf ? ahi : alo;
    }

    f32x16 fwdE, fwdO;
#pragma unroll
    for (int r = 0; r < 16; ++r) { fwdE[r] = 3.0e38f; fwdO[r] = 3.0e38f; }

    const f32x16 zero = {};
    const float* rb = ref + (size_t)b * 3 * M + cs * 2048;

    for (int ch = 0; ch < 2; ++ch) {
        __syncthreads();   // previous chunk fully consumed before overwrite
        {
            // stage 1024 augmented B cols: 4 consecutive cols per thread,
            // float4 loads per coordinate row, XOR-swizzled LDS rows
            const int c0 = tid * 4;      // within-chunk col base
            const float4 vx = *reinterpret_cast<const float4*>(&rb[0 * M + ch * 1024 + c0]);
            const float4 vy = *reinterpret_cast<const float4*>(&rb[1 * M + ch * 1024 + c0]);
            const float4 vz = *reinterpret_cast<const float4*>(&rb[2 * M + ch * 1024 + c0]);
            const float xs[4] = {vx.x, vx.y, vx.z, vx.w};
            const float ys[4] = {vy.x, vy.y, vy.z, vy.w};
            const float zs[4] = {vz.x, vz.y, vz.z, vz.w};
#pragma unroll
            for (int k = 0; k < 4; ++k) {
                const float x = xs[k], y = ys[k], z = zs[k];
                const float d2 = x * x + y * y + z * z;
                const unsigned short xh = bf16_of(x), xl = bf16_of(x - bf16_to_f(xh));
                const unsigned short yh = bf16_of(y), yl = bf16_of(y - bf16_to_f(yh));
                const unsigned short zh = bf16_of(z), zl = bf16_of(z - bf16_to_f(zh));
                const unsigned short d2h = bf16_of(d2);
                const unsigned short d2l = bf16_of(d2 - bf16_to_f(d2h));
                const unsigned short one = 0x3F80;
                bf16x8 v0, v1;
                v0[0]=(short)xh; v0[1]=(short)xl; v0[2]=(short)xh; v0[3]=(short)xl;
                v0[4]=(short)yh; v0[5]=(short)yl; v0[6]=(short)yh; v0[7]=(short)yl;
                v1[0]=(short)zh; v1[1]=(short)zl; v1[2]=(short)zh; v1[3]=(short)zl;
                v1[4]=(short)one; v1[5]=(short)one; v1[6]=(short)d2h; v1[7]=(short)d2l;
                const int c = c0 + k;
                const int swz = c ^ ((c >> 3) & 7);   // bijective, both-side min
                *reinterpret_cast<bf16x8*>(&bstage[0][swz][0]) = v0;
                *reinterpret_cast<bf16x8*>(&bstage[1][swz][0]) = v1;
            }
        }
        __syncthreads();

        // 32 tiles, 2 per step: 2 ds_read_b128 + 2 MFMA + 32 v_min (E/O chains)
#pragma unroll 4
        for (int i = 0; i < 16; ++i) {
            const bf16x8 bf0 = *reinterpret_cast<const bf16x8*>(&bstage[hf][i * 64 + sA][0]);
            const bf16x8 bf1 = *reinterpret_cast<const bf16x8*>(&bstage[hf][i * 64 + sB][0]);
            const f32x16 acc0 = __builtin_amdgcn_mfma_f32_32x32x16_bf16(afrag, bf0, zero, 0, 0, 0);
            const f32x16 acc1 = __builtin_amdgcn_mfma_f32_32x32x16_bf16(afrag, bf1, zero, 0, 0, 0);
#pragma unroll
            for (int r = 0; r < 16; ++r) {
                fwdE[r] = fminf(fwdE[r], acc0[r]);   // plain v_min — NO min3
                fwdO[r] = fminf(fwdO[r], acc1[r]);
            }
        }
    }

    f32x16 fwd;
#pragma unroll
    for (int r = 0; r < 16; ++r) fwd[r] = fminf(fwdE[r], fwdO[r]);

    // butterfly min across the 32-lane col dimension (halves = distinct rows)
#pragma unroll
    for (int r = 0; r < 16; ++r) {
        float vv = fwd[r];
        vv = fminf(vv, __shfl_xor(vv, 1));
        vv = fminf(vv, __shfl_xor(vv, 2));
        vv = fminf(vv, __shfl_xor(vv, 4));
        vv = fminf(vv, __shfl_xor(vv, 8));
        vv = fminf(vv, __shfl_xor(vv, 16));
        fwd[r] = vv;
    }
    if (l31 == 0) {   // lanes 0 (row-half 0) and 32 (row-half 1): 16 row-mins each
        float* pf = part + ((size_t)cs * 16 + dir * 8 + b) * M
                  + rg * 128 + wave * 32 + hf * 4;
#pragma unroll
        for (int r = 0; r < 16; ++r)
            pf[(r & 3) + 8 * (r >> 2)] = fwd[r];
    }
}

// 256 blocks x 256 threads: min over 2 col-splits, sqrt, block-sum, and
// 3 scaled atomicAdds into out (final kernel fused away)
__global__ __launch_bounds__(256) void chamfer_reduce(
    const float* __restrict__ part, float* __restrict__ out)
{
    const int idx = blockIdx.x * 256 + threadIdx.x;   // [0, 2*B*M)
    const int row = idx & (M - 1);
    const int db  = idx >> 12;                        // dir*8 + b

    const float* p = part + (size_t)db * M + row;
    const float v = fminf(p[0], p[(size_t)16 * M]);

    float s = sqrtf(fmaxf(v, 0.0f));
#pragma unroll
    for (int off = 32; off > 0; off >>= 1) s += __shfl_down(s, off);
    __shared__ float partial[4];
    if ((threadIdx.x & 63) == 0) partial[threadIdx.x >> 6] = s;
    __syncthreads();
    if (threadIdx.x == 0) {
        const float tot = (partial[0] + partial[1] + partial[2] + partial[3])
                        * (1.0f / (float)(B * M));   // fwd /(B*M), bwd /(B*N), M==N
        atomicAdd(&out[0], tot);
        atomicAdd(&out[1], tot);
        atomicAdd(&out[2], tot);
    }
}

extern "C" void kernel_launch(void* const* d_in, const int* in_sizes, int n_in,
                              void* d_out, int out_size, void* d_ws, size_t ws_size,
                              hipStream_t stream)
{
    const float* src = (const float*)d_in[0];   // [B,3,M]
    const float* dst = (const float*)d_in[1];   // [B,3,N]
    float* out = (float*)d_out;                 // 3 floats

    float* part = (float*)d_ws;                 // 512 KB, fully written

    chamfer_main  <<<1024, 256, 0, stream>>>(src, dst, part, out);
    chamfer_reduce<<<256, 256, 0, stream>>>(part, out);
}

// Round 21
// 22.046 us; speedup vs baseline: 1.3567x; 1.3567x over previous
//
#include <hip/hip_runtime.h>
#include <math.h>

// Chamfer loss, B=8, C=3, M=N=4096, fp32 — MFMA, round 21 = EXACT round-16
// revert (22.0 us session best). Confirmation run.
//
// sq[m][n] = s2[m] + d2[n] - 2 s.d as a K=16 bf16 GEMM with hi/lo split:
//   A_m = [-2xh,-2xh,-2xl,-2xl | y.. | z.. | s2h,s2l,1,1]   (query rows)
//   B_n = [ xh,  xl,  xh,  xl  | y.. | z.. | 1,1,d2h,d2l]   (reference cols)
// C layout (m74/m101): col = lane&31, row = (reg&3) + 8*(reg>>2) + 4*(lane>>5)
//
// Converged structure & the lever ledger that proves it:
//   occupancy 2->4 waves/SIMD: x1.7 win (r10); 4->6/8: loss (r11/r19)
//   XOR swizzle c^((c>>3)&7): -1 us (r16, kept — write+read conflict-free)
//   LDS-read halving: null (r13/r18) ; butterfly removal: null (r17)
//   v_min3 in hot loop: +8 us poison (r11/r12/r14) — plain v_min only
//   dispatch fusion w/ same-line atomics: +8 us poison (r20) — 768 atomicAdds
//     on one cacheline serialize at L2; keep bsums + 1-block final
//   memsets in graph: ~11 us poison (r9) — zero memsets, plain stores only

constexpr int B = 8;
constexpr int M = 4096;   // == N

typedef __attribute__((ext_vector_type(8)))  short bf16x8;
typedef __attribute__((ext_vector_type(16))) float f32x16;

__device__ inline unsigned short bf16_of(float x) {   // round-to-nearest-even
    unsigned int u = __float_as_uint(x);
    u += 0x7FFFu + ((u >> 16) & 1u);
    return (unsigned short)(u >> 16);
}
__device__ inline float bf16_to_f(unsigned short h) {
    return __uint_as_float(((unsigned int)h) << 16);
}

// ws: part [2 cs][16 db][M] f32 @ 0   (512 KB) ; bsums [256] f32 @ 512 KB

// grid 1024 = (dir<<9 | b<<6 | rg<<1 | cs); 256 thr = 4 waves
// wave w: rows rg*128 + w*32 .. +32 ; cols cs*2048 .. +2048 (2 chunks of 1024)
__global__ __launch_bounds__(256, 4) void chamfer_main(
    const float* __restrict__ src,
    const float* __restrict__ dst,
    float* __restrict__ part)
{
    int bid = blockIdx.x;
    const int cs  = bid & 1;  bid >>= 1;
    const int rg  = bid & 31; bid >>= 5;
    const int b   = bid & 7;  bid >>= 3;
    const int dir = bid;      // 0: rows=src scan dst ; 1: rows=dst scan src

    const float* __restrict__ qry = dir ? dst : src;   // A-side (rows)
    const float* __restrict__ ref = dir ? src : dst;   // B-side (cols)

    const int tid  = threadIdx.x;
    const int wave = tid >> 6;
    const int l31  = tid & 31;
    const int hf   = (tid >> 5) & 1;    // k-group / row-half within wave

    __shared__ __align__(16) unsigned short bstage[2][1024][8];  // 32 KB

    // per-lane swizzled read rows: col i*64+l31 -> i*64 + sA ; +32 -> i*64 + sB
    const int sA = l31 ^ (l31 >> 3);
    const int sB = 32 + (l31 ^ (4 | (l31 >> 3)));

    // ---- augmented A fragment for this lane's row (constant across scan) ----
    bf16x8 afrag;
    {
        const int mrow = rg * 128 + wave * 32 + l31;
        const float* qb = qry + (size_t)b * 3 * M;
        const float x = qb[0 * M + mrow];
        const float y = qb[1 * M + mrow];
        const float z = qb[2 * M + mrow];
        const float s2 = x * x + y * y + z * z;
        const float xhf = bf16_to_f(bf16_of(x));
        const float yhf = bf16_to_f(bf16_of(y));
        const float zhf = bf16_to_f(bf16_of(z));
        // -2*hi exact (pow2 scale of a bf16 value)
        const unsigned short nxh = bf16_of(-2.0f * xhf), nxl = bf16_of(-2.0f * (x - xhf));
        const unsigned short nyh = bf16_of(-2.0f * yhf), nyl = bf16_of(-2.0f * (y - yhf));
        const unsigned short nzh = bf16_of(-2.0f * zhf), nzl = bf16_of(-2.0f * (z - zhf));
        const unsigned short s2h = bf16_of(s2);
        const unsigned short s2l = bf16_of(s2 - bf16_to_f(s2h));
        const unsigned short one = 0x3F80;
        bf16x8 alo, ahi;
        alo[0]=(short)nxh; alo[1]=(short)nxh; alo[2]=(short)nxl; alo[3]=(short)nxl;
        alo[4]=(short)nyh; alo[5]=(short)nyh; alo[6]=(short)nyl; alo[7]=(short)nyl;
        ahi[0]=(short)nzh; ahi[1]=(short)nzh; ahi[2]=(short)nzl; ahi[3]=(short)nzl;
        ahi[4]=(short)s2h; ahi[5]=(short)s2l; ahi[6]=(short)one; ahi[7]=(short)one;
        afrag = hf ? ahi : alo;
    }

    f32x16 fwdE, fwdO;
#pragma unroll
    for (int r = 0; r < 16; ++r) { fwdE[r] = 3.0e38f; fwdO[r] = 3.0e38f; }

    const f32x16 zero = {};
    const float* rb = ref + (size_t)b * 3 * M + cs * 2048;

    for (int ch = 0; ch < 2; ++ch) {
        __syncthreads();   // previous chunk fully consumed before overwrite
        {
            // stage 1024 augmented B cols: 4 consecutive cols per thread,
            // float4 loads per coordinate row, XOR-swizzled LDS rows
            const int c0 = tid * 4;      // within-chunk col base
            const float4 vx = *reinterpret_cast<const float4*>(&rb[0 * M + ch * 1024 + c0]);
            const float4 vy = *reinterpret_cast<const float4*>(&rb[1 * M + ch * 1024 + c0]);
            const float4 vz = *reinterpret_cast<const float4*>(&rb[2 * M + ch * 1024 + c0]);
            const float xs[4] = {vx.x, vx.y, vx.z, vx.w};
            const float ys[4] = {vy.x, vy.y, vy.z, vy.w};
            const float zs[4] = {vz.x, vz.y, vz.z, vz.w};
#pragma unroll
            for (int k = 0; k < 4; ++k) {
                const float x = xs[k], y = ys[k], z = zs[k];
                const float d2 = x * x + y * y + z * z;
                const unsigned short xh = bf16_of(x), xl = bf16_of(x - bf16_to_f(xh));
                const unsigned short yh = bf16_of(y), yl = bf16_of(y - bf16_to_f(yh));
                const unsigned short zh = bf16_of(z), zl = bf16_of(z - bf16_to_f(zh));
                const unsigned short d2h = bf16_of(d2);
                const unsigned short d2l = bf16_of(d2 - bf16_to_f(d2h));
                const unsigned short one = 0x3F80;
                bf16x8 v0, v1;
                v0[0]=(short)xh; v0[1]=(short)xl; v0[2]=(short)xh; v0[3]=(short)xl;
                v0[4]=(short)yh; v0[5]=(short)yl; v0[6]=(short)yh; v0[7]=(short)yl;
                v1[0]=(short)zh; v1[1]=(short)zl; v1[2]=(short)zh; v1[3]=(short)zl;
                v1[4]=(short)one; v1[5]=(short)one; v1[6]=(short)d2h; v1[7]=(short)d2l;
                const int c = c0 + k;
                const int swz = c ^ ((c >> 3) & 7);   // bijective, both-side min
                *reinterpret_cast<bf16x8*>(&bstage[0][swz][0]) = v0;
                *reinterpret_cast<bf16x8*>(&bstage[1][swz][0]) = v1;
            }
        }
        __syncthreads();

        // 32 tiles, 2 per step: 2 ds_read_b128 + 2 MFMA + 32 v_min (E/O chains)
#pragma unroll 4
        for (int i = 0; i < 16; ++i) {
            const bf16x8 bf0 = *reinterpret_cast<const bf16x8*>(&bstage[hf][i * 64 + sA][0]);
            const bf16x8 bf1 = *reinterpret_cast<const bf16x8*>(&bstage[hf][i * 64 + sB][0]);
            const f32x16 acc0 = __builtin_amdgcn_mfma_f32_32x32x16_bf16(afrag, bf0, zero, 0, 0, 0);
            const f32x16 acc1 = __builtin_amdgcn_mfma_f32_32x32x16_bf16(afrag, bf1, zero, 0, 0, 0);
#pragma unroll
            for (int r = 0; r < 16; ++r) {
                fwdE[r] = fminf(fwdE[r], acc0[r]);   // plain v_min — NO min3
                fwdO[r] = fminf(fwdO[r], acc1[r]);
            }
        }
    }

    f32x16 fwd;
#pragma unroll
    for (int r = 0; r < 16; ++r) fwd[r] = fminf(fwdE[r], fwdO[r]);

    // butterfly min across the 32-lane col dimension (halves = distinct rows)
#pragma unroll
    for (int r = 0; r < 16; ++r) {
        float vv = fwd[r];
        vv = fminf(vv, __shfl_xor(vv, 1));
        vv = fminf(vv, __shfl_xor(vv, 2));
        vv = fminf(vv, __shfl_xor(vv, 4));
        vv = fminf(vv, __shfl_xor(vv, 8));
        vv = fminf(vv, __shfl_xor(vv, 16));
        fwd[r] = vv;
    }
    if (l31 == 0) {   // lanes 0 (row-half 0) and 32 (row-half 1): 16 row-mins each
        float* pf = part + ((size_t)cs * 16 + dir * 8 + b) * M
                  + rg * 128 + wave * 32 + hf * 4;
#pragma unroll
        for (int r = 0; r < 16; ++r)
            pf[(r & 3) + 8 * (r >> 2)] = fwd[r];
    }
}

// 256 blocks x 256 threads: min over the 2 col-splits, sqrt, block-sum -> bsums
__global__ __launch_bounds__(256) void chamfer_reduce(
    const float* __restrict__ part, float* __restrict__ bsums)
{
    const int idx = blockIdx.x * 256 + threadIdx.x;   // [0, 2*B*M)
    const int row = idx & (M - 1);
    const int db  = idx >> 12;                        // dir*8 + b

    const float* p = part + (size_t)db * M + row;
    const float v = fminf(p[0], p[(size_t)16 * M]);

    float s = sqrtf(fmaxf(v, 0.0f));
#pragma unroll
    for (int off = 32; off > 0; off >>= 1) s += __shfl_down(s, off);
    __shared__ float partial[4];
    if ((threadIdx.x & 63) == 0) partial[threadIdx.x >> 6] = s;
    __syncthreads();
    if (threadIdx.x == 0)
        bsums[blockIdx.x] = partial[0] + partial[1] + partial[2] + partial[3];
}

// 1 block: total, scale, plain-store out[0..2] (no memset needed anywhere)
__global__ __launch_bounds__(256) void chamfer_final(
    const float* __restrict__ bsums, float* __restrict__ out)
{
    float s = bsums[threadIdx.x];
#pragma unroll
    for (int off = 32; off > 0; off >>= 1) s += __shfl_down(s, off);
    __shared__ float partial[4];
    if ((threadIdx.x & 63) == 0) partial[threadIdx.x >> 6] = s;
    __syncthreads();
    if (threadIdx.x == 0) {
        const float tot = (partial[0] + partial[1] + partial[2] + partial[3])
                        * (1.0f / (float)(B * M));   // fwd /(B*M), bwd /(B*N), M==N
        out[0] = tot;
        out[1] = tot;
        out[2] = tot;
    }
}

extern "C" void kernel_launch(void* const* d_in, const int* in_sizes, int n_in,
                              void* d_out, int out_size, void* d_ws, size_t ws_size,
                              hipStream_t stream)
{
    const float* src = (const float*)d_in[0];   // [B,3,M]
    const float* dst = (const float*)d_in[1];   // [B,3,N]
    float* out = (float*)d_out;                 // 3 floats

    float* part  = (float*)d_ws;                          // 512 KB, fully written
    float* bsums = (float*)((char*)d_ws + (1u << 19));    // 256 floats, fully written

    chamfer_main  <<<1024, 256, 0, stream>>>(src, dst, part);
    chamfer_reduce<<<256, 256, 0, stream>>>(part, bsums);
    chamfer_final <<<1, 256, 0, stream>>>(bsums, out);
}